// Round 8
// baseline (302.882 us; speedup 1.0000x reference)
//
#include <hip/hip_runtime.h>
#include <cstdint>
#include <cstddef>

#define NEGV  -1.0e9f
// 0.125 * log2(e): attention computed in exp2 units
#define QSCALE 0.18033688011112042f

typedef _Float16 h8 __attribute__((ext_vector_type(8)));
typedef _Float16 h4 __attribute__((ext_vector_type(4)));
typedef _Float16 h2 __attribute__((ext_vector_type(2)));
typedef float    f4 __attribute__((ext_vector_type(4)));
typedef float    f16x __attribute__((ext_vector_type(16)));
typedef unsigned int u32x4 __attribute__((ext_vector_type(4)));

// ---------------------------------------------------------------------------
// ws layout (f16 elements):
//  Wqt: [3][1536][512]  (W^T)   2359296
//  Wot: [3][512][512]   (W^T)    786432
//  Qh : [3][8][8][512][64] (q*QSCALE)  6291456
//  Kh : [8][8][1536][64]        6291456
//  Vt : [8][8][64][1536] (V^T)  6291456
//  Oh : [3][4096][512]          6291456
// ---------------------------------------------------------------------------

static __device__ inline h8 cvt8(float4 a, float4 b) {
    h8 r = { (_Float16)a.x, (_Float16)a.y, (_Float16)a.z, (_Float16)a.w,
             (_Float16)b.x, (_Float16)b.y, (_Float16)b.z, (_Float16)b.w };
    return r;
}

// ========== merged W transpose+cvt: Wqkv (512x1536) and Wout (512x512) ==========
__global__ __launch_bounds__(256) void wt_cvt(
    const float* __restrict__ q0, const float* __restrict__ q1, const float* __restrict__ q2,
    const float* __restrict__ o0, const float* __restrict__ o1, const float* __restrict__ o2,
    _Float16* __restrict__ Wqt, _Float16* __restrict__ Wot)
{
    const int mod = blockIdx.z;
    const int flat = blockIdx.x;
    const float* s;
    _Float16* d;
    int C, bx, by;
    if (flat < 768) {
        C = 1536; bx = flat % 48; by = flat / 48;
        s = (mod == 0) ? q0 : ((mod == 1) ? q1 : q2);
        d = Wqt + (size_t)mod * 1536 * 512;
    } else {
        C = 512; bx = (flat - 768) % 16; by = (flat - 768) / 16;
        s = (mod == 0) ? o0 : ((mod == 1) ? o1 : o2);
        d = Wot + (size_t)mod * 512 * 512;
    }
    const int c0 = bx * 32, r0 = by * 32;
    __shared__ float tile[32][33];
    const int tr = threadIdx.x >> 3;
    const int tc = (threadIdx.x & 7) * 4;
    float4 v = *reinterpret_cast<const float4*>(&s[(size_t)(r0 + tr) * C + c0 + tc]);
    tile[tr][tc + 0] = v.x; tile[tr][tc + 1] = v.y; tile[tr][tc + 2] = v.z; tile[tr][tc + 3] = v.w;
    __syncthreads();
    h4 o = { (_Float16)tile[tc + 0][tr], (_Float16)tile[tc + 1][tr],
             (_Float16)tile[tc + 2][tr], (_Float16)tile[tc + 3][tr] };
    *reinterpret_cast<h4*>(&d[(size_t)(c0 + tr) * 512 + r0 + tc]) = o;
}

// ======================= QKV projection (f16 MFMA, BK=64) =======================
__global__ __launch_bounds__(256) void qkv_gemm_f16(
    const float* __restrict__ x0, const float* __restrict__ x1, const float* __restrict__ x2,
    const _Float16* __restrict__ Wqt,
    _Float16* __restrict__ Qh, _Float16* __restrict__ Kh, _Float16* __restrict__ Vt)
{
    const int mod = blockIdx.z;
    const float* __restrict__ A = (mod == 0) ? x0 : ((mod == 1) ? x1 : x2);
    const _Float16* __restrict__ Bw = Wqt + (size_t)mod * 1536 * 512;

    __shared__ _Float16 smem[2 * 128 * 72];   // 36864 B
    _Float16* As = smem;                 // [m][k] stride 72
    _Float16* Bs = smem + 128 * 72;      // [n][k]

    const int t = threadIdx.x;
    const int brow = blockIdx.x * 128, bcol = blockIdx.y * 128;
    const int w = t >> 6, l = t & 63;
    const int wr = (w >> 1) * 64, wc = (w & 1) * 64;
    const int lr = l & 15, lg = l >> 4, lk = lg * 8;

    const int sm = t >> 1, sk = (t & 1) * 32;
    const float*    __restrict__ aRow = &A [(size_t)(brow + sm) * 512 + sk];
    const _Float16* __restrict__ bRow = &Bw[(size_t)(bcol + sm) * 512 + sk];
    _Float16* aDst = &As[sm * 72 + sk];
    _Float16* bDst = &Bs[sm * 72 + sk];

    f4 acc[4][4] = {};
    float4 ax[8];
    h8 bx[4];

#pragma unroll
    for (int j = 0; j < 8; j++) ax[j] = *reinterpret_cast<const float4*>(&aRow[j * 4]);
#pragma unroll
    for (int j = 0; j < 4; j++) bx[j] = *reinterpret_cast<const h8*>(&bRow[j * 8]);
#pragma unroll
    for (int j = 0; j < 4; j++) {
        *reinterpret_cast<h8*>(&aDst[j * 8]) = cvt8(ax[2 * j], ax[2 * j + 1]);
        *reinterpret_cast<h8*>(&bDst[j * 8]) = bx[j];
    }

    for (int k0 = 0; k0 < 512; k0 += 64) {
        __syncthreads();
        const bool more = (k0 + 64) < 512;
        if (more) {
            const int kn = k0 + 64;
#pragma unroll
            for (int j = 0; j < 8; j++) ax[j] = *reinterpret_cast<const float4*>(&aRow[kn + j * 4]);
#pragma unroll
            for (int j = 0; j < 4; j++) bx[j] = *reinterpret_cast<const h8*>(&bRow[kn + j * 8]);
        }
#pragma unroll
        for (int ks = 0; ks < 64; ks += 32) {
            h8 af[4], bf[4];
#pragma unroll
            for (int m = 0; m < 4; m++)
                af[m] = *reinterpret_cast<h8*>(&As[(wr + m * 16 + lr) * 72 + ks + lk]);
#pragma unroll
            for (int n = 0; n < 4; n++)
                bf[n] = *reinterpret_cast<h8*>(&Bs[(wc + n * 16 + lr) * 72 + ks + lk]);
            __builtin_amdgcn_s_setprio(1);
#pragma unroll
            for (int m = 0; m < 4; m++)
#pragma unroll
                for (int n = 0; n < 4; n++)
                    acc[m][n] = __builtin_amdgcn_mfma_f32_16x16x32_f16(af[m], bf[n], acc[m][n], 0, 0, 0);
            __builtin_amdgcn_s_setprio(0);
        }
        __syncthreads();
        if (more) {
#pragma unroll
            for (int j = 0; j < 4; j++) {
                *reinterpret_cast<h8*>(&aDst[j * 8]) = cvt8(ax[2 * j], ax[2 * j + 1]);
                *reinterpret_cast<h8*>(&bDst[j * 8]) = bx[j];
            }
        }
    }

    const int sec = bcol >> 9;                    // 0=q 1=k 2=v
    const int b = brow >> 9;
    const int nbase = brow & 511;
    const int cbase = bcol - (sec << 9);

    if (sec == 2) {
#pragma unroll
        for (int m = 0; m < 4; m++) {
            const int n = nbase + wr + m * 16 + lg * 4;
#pragma unroll
            for (int nn = 0; nn < 4; nn++) {
                const int cis = cbase + wc + nn * 16 + lr;
                const int hh = cis >> 6, d = cis & 63;
                h4 pv = { (_Float16)acc[m][nn][0], (_Float16)acc[m][nn][1],
                          (_Float16)acc[m][nn][2], (_Float16)acc[m][nn][3] };
                *reinterpret_cast<h4*>(&Vt[(((size_t)b * 8 + hh) * 64 + d) * 1536 + mod * 512 + n]) = pv;
            }
        }
    } else {
        const float scl = (sec == 0) ? QSCALE : 1.0f;
        _Float16 (*Ts)[136] = reinterpret_cast<_Float16(*)[136]>(smem);
#pragma unroll
        for (int pass = 0; pass < 2; pass++) {
            __syncthreads();
            if ((w >> 1) == pass) {
#pragma unroll
                for (int m = 0; m < 4; m++)
#pragma unroll
                    for (int nn = 0; nn < 4; nn++)
#pragma unroll
                        for (int reg = 0; reg < 4; reg++)
                            Ts[m * 16 + lg * 4 + reg][wc + nn * 16 + lr] =
                                (_Float16)(acc[m][nn][reg] * scl);
            }
            __syncthreads();
#pragma unroll
            for (int it = 0; it < 4; it++) {
                const int idx = t + it * 256;
                const int r = idx >> 4, c = (idx & 15) * 8;
                h8 v = *reinterpret_cast<h8*>(&Ts[r][c]);
                const int n = nbase + pass * 64 + r;
                const int cis = cbase + c;
                const int hh = cis >> 6, d = cis & 63;
                if (sec == 0)
                    *reinterpret_cast<h8*>(&Qh[((((size_t)mod * 8 + b) * 8 + hh) * 512 + n) * 64 + d]) = v;
                else
                    *reinterpret_cast<h8*>(&Kh[(((size_t)b * 8 + hh) * 1536 + mod * 512 + n) * 64 + d]) = v;
            }
        }
    }
}

// ======================= attention: 32x32 MFMA, K from L2, P in registers =======================
// block: 128 thr = 2 waves; wave owns 64 q (2 col-blocks of 32). QBLK=128.
// grid (bh, 4 qtiles, mod): bh-major keeps K/V sharers on one XCD.
// LDS: only V (8KB, XOR-swizzled). K-frags loaded global->reg (L2-hot).
// P built in-register: cvt_pkrtz + shfl_xor(32) (no Ps LDS).
__global__ __launch_bounds__(128) void attn_f16(
    const _Float16* __restrict__ Qh, const _Float16* __restrict__ Kh, const _Float16* __restrict__ Vt,
    const int* __restrict__ m0, const int* __restrict__ m1, const int* __restrict__ m2,
    _Float16* __restrict__ Oh)
{
    const int mod = blockIdx.z;
    const int bh = blockIdx.x, b = bh >> 3, h = bh & 7;
    const int q0 = blockIdx.y * 128;

    __shared__ _Float16 Vs[64 * 64];   // [d][key] XOR-swizzled 16B segs

    const int t = threadIdx.x, w = t >> 6, l = t & 63;
    const int r = l & 31, hi = l >> 5;

    // Q B-frags: [col=q 32][k=d 16] per dk; lane holds Q[q=r][dk*16 + hi*8 ..+7]
    const _Float16* __restrict__ Qp = Qh + ((((size_t)mod * 8 + b) * 8 + h) * 512 + q0 + w * 64) * 64;
    h8 qf[2][4];
#pragma unroll
    for (int qb = 0; qb < 2; qb++)
#pragma unroll
        for (int dk = 0; dk < 4; dk++)
            qf[qb][dk] = *reinterpret_cast<const h8*>(&Qp[(size_t)(qb * 32 + r) * 64 + dk * 16 + hi * 8]);

    const int* __restrict__ mk = (mod == 0) ? m0 : ((mod == 1) ? m1 : m2);
    bool msk[2];
#pragma unroll
    for (int qb = 0; qb < 2; qb++)
        msk[qb] = mk[b * 512 + q0 + w * 64 + qb * 32 + r] != 0;

    float mrow[2] = { -3.0e38f, -3.0e38f };
    float lsum[2] = { 0.f, 0.f };
    f16x o[2][2] = {};   // [qb][dg]: O^T[d=dg*32+row(reg,hi)][q=r]

    const _Float16* __restrict__ Kp = Kh + (size_t)bh * 1536 * 64;
    const _Float16* __restrict__ Vp = Vt + (size_t)bh * 64 * 1536;

    // V staging: thread covers d-row vr, segs vs4..vs4+3 (16B each), XOR-swizzled
    const int vr = t >> 1, vs4 = (t & 1) * 4;
    h8 vrg[4];
#pragma unroll
    for (int j = 0; j < 4; j++)
        vrg[j] = *reinterpret_cast<const h8*>(&Vp[(size_t)vr * 1536 + (vs4 + j) * 8]);
#pragma unroll
    for (int j = 0; j < 4; j++)
        *reinterpret_cast<h8*>(&Vs[vr * 64 + (((vs4 + j) ^ (vr & 7)) * 8)]) = vrg[j];

    // K prefetch for first 32-key step
    h8 kn[4];
#pragma unroll
    for (int dk = 0; dk < 4; dk++)
        kn[dk] = *reinterpret_cast<const h8*>(&Kp[(size_t)r * 64 + dk * 16 + hi * 8]);

    for (int c0 = 0; c0 < 1536; c0 += 64) {
        __syncthreads();                       // staged V visible
        const bool more = (c0 + 64) < 1536;
        if (more) {                            // issue next-chunk V loads early
#pragma unroll
            for (int j = 0; j < 4; j++)
                vrg[j] = *reinterpret_cast<const h8*>(&Vp[(size_t)vr * 1536 + c0 + 64 + (vs4 + j) * 8]);
        }

#pragma unroll
        for (int s32 = 0; s32 < 2; s32++) {
            h8 kc[4];
#pragma unroll
            for (int dk = 0; dk < 4; dk++) kc[dk] = kn[dk];
            // prefetch next 32-key K step
            if (s32 == 0 || more) {
                const int nc = (s32 == 0) ? (c0 + 32) : (c0 + 64);
#pragma unroll
                for (int dk = 0; dk < 4; dk++)
                    kn[dk] = *reinterpret_cast<const h8*>(&Kp[(size_t)(nc + r) * 64 + dk * 16 + hi * 8]);
            }

            // S^T = K Q^T : C[row=key(reg,hi)][col=q=r], one 32x32 per qb
            f16x st[2] = {};
            __builtin_amdgcn_s_setprio(1);
#pragma unroll
            for (int dk = 0; dk < 4; dk++) {
                st[0] = __builtin_amdgcn_mfma_f32_32x32x16_f16(kc[dk], qf[0][dk], st[0], 0, 0, 0);
                st[1] = __builtin_amdgcn_mfma_f32_32x32x16_f16(kc[dk], qf[1][dk], st[1], 0, 0, 0);
            }
            __builtin_amdgcn_s_setprio(0);

            u32x4 pbw[2][2];
#pragma unroll
            for (int qb = 0; qb < 2; qb++) {
                if (!msk[qb]) {
#pragma unroll
                    for (int reg = 0; reg < 16; reg++) st[qb][reg] = NEGV;
                }
                float cm = st[qb][0];
#pragma unroll
                for (int reg = 1; reg < 16; reg++) cm = fmaxf(cm, st[qb][reg]);
                cm = fmaxf(cm, __shfl_xor(cm, 32));

                if (!__all(cm <= mrow[qb] + 8.0f)) {   // defer-max
                    const float mn = fmaxf(mrow[qb], cm);
                    const float sc = __builtin_amdgcn_exp2f(mrow[qb] - mn);
                    mrow[qb] = mn;
                    lsum[qb] *= sc;
                    o[qb][0] *= sc;
                    o[qb][1] *= sc;
                }

                float p[16];
                float rs = 0.f;
#pragma unroll
                for (int reg = 0; reg < 16; reg++) {
                    p[reg] = __builtin_amdgcn_exp2f(st[qb][reg] - mrow[qb]);
                    rs += p[reg];
                }
                rs += __shfl_xor(rs, 32);
                lsum[qb] += rs;

                // B-frag assembly: keys kk*16 + hi*8 + j for this lane's q
#pragma unroll
                for (int kk = 0; kk < 2; kk++) {
                    unsigned int a0 = __builtin_bit_cast(unsigned int,
                        __builtin_amdgcn_cvt_pkrtz(p[8 * kk + 0], p[8 * kk + 1]));
                    unsigned int a1 = __builtin_bit_cast(unsigned int,
                        __builtin_amdgcn_cvt_pkrtz(p[8 * kk + 2], p[8 * kk + 3]));
                    unsigned int b0 = __builtin_bit_cast(unsigned int,
                        __builtin_amdgcn_cvt_pkrtz(p[8 * kk + 4], p[8 * kk + 5]));
                    unsigned int b1 = __builtin_bit_cast(unsigned int,
                        __builtin_amdgcn_cvt_pkrtz(p[8 * kk + 6], p[8 * kk + 7]));
                    const unsigned int ra0 = __shfl_xor(a0, 32);
                    const unsigned int ra1 = __shfl_xor(a1, 32);
                    const unsigned int rb0 = __shfl_xor(b0, 32);
                    const unsigned int rb1 = __shfl_xor(b1, 32);
                    u32x4 pw;
                    if (hi == 0) { pw[0] = a0; pw[1] = a1; pw[2] = ra0; pw[3] = ra1; }
                    else         { pw[0] = rb0; pw[1] = rb1; pw[2] = b0; pw[3] = b1; }
                    pbw[qb][kk] = pw;
                }
            }

            // O^T += V^T P : A = V^T[32 d][16 k] from swizzled LDS, each read feeds 2 qb
            __builtin_amdgcn_s_setprio(1);
#pragma unroll
            for (int kk = 0; kk < 2; kk++) {
                const h8 pb0 = __builtin_bit_cast(h8, pbw[0][kk]);
                const h8 pb1 = __builtin_bit_cast(h8, pbw[1][kk]);
#pragma unroll
                for (int dg = 0; dg < 2; dg++) {
                    h8 va = *reinterpret_cast<h8*>(
                        &Vs[(dg * 32 + r) * 64 + (((s32 * 4 + kk * 2 + hi) ^ (r & 7)) * 8)]);
                    o[0][dg] = __builtin_amdgcn_mfma_f32_32x32x16_f16(va, pb0, o[0][dg], 0, 0, 0);
                    o[1][dg] = __builtin_amdgcn_mfma_f32_32x32x16_f16(va, pb1, o[1][dg], 0, 0, 0);
                }
            }
            __builtin_amdgcn_s_setprio(0);
        }

        __syncthreads();                       // all V reads done
        if (more) {                            // write-late
#pragma unroll
            for (int j = 0; j < 4; j++)
                *reinterpret_cast<h8*>(&Vs[vr * 64 + (((vs4 + j) ^ (vr & 7)) * 8)]) = vrg[j];
        }
    }

    // store O: lane holds O^T[d = dg*32 + (reg&3)+8*(reg>>2)+4*hi][q = r]
#pragma unroll
    for (int qb = 0; qb < 2; qb++) {
        const float inv = 1.f / lsum[qb];
        const size_t row = (size_t)mod * 4096 + b * 512 + q0 + w * 64 + qb * 32 + r;
#pragma unroll
        for (int dg = 0; dg < 2; dg++)
#pragma unroll
            for (int a = 0; a < 4; a++) {
                h4 ov = { (_Float16)(o[qb][dg][4 * a + 0] * inv),
                          (_Float16)(o[qb][dg][4 * a + 1] * inv),
                          (_Float16)(o[qb][dg][4 * a + 2] * inv),
                          (_Float16)(o[qb][dg][4 * a + 3] * inv) };
                *reinterpret_cast<h4*>(&Oh[row * 512 + h * 64 + dg * 32 + a * 8 + hi * 4]) = ov;
            }
    }
}

// ======================= output projection (BM=64, BN=128, BK=64) =======================
__global__ __launch_bounds__(256) void out_gemm_f16(
    const _Float16* __restrict__ Oh, const _Float16* __restrict__ Wot,
    float* __restrict__ out)
{
    const int mod = blockIdx.z;
    const _Float16* __restrict__ A  = Oh  + (size_t)mod * 4096 * 512;
    const _Float16* __restrict__ Bw = Wot + (size_t)mod * 512 * 512;
    float* __restrict__ C = out + (size_t)mod * 4096 * 512;

    __shared__ _Float16 smem[(64 + 128) * 72];   // 27648 B
    _Float16* As = smem;                 // [m 64][k 72]
    _Float16* Bs = smem + 64 * 72;       // [n 128][k 72]

    const int t = threadIdx.x;
    const int brow = blockIdx.x * 64, bcol = blockIdx.y * 128;
    const int w = t >> 6, l = t & 63;
    const int wr = (w >> 1) * 32, wc = (w & 1) * 64;
    const int lr = l & 15, lg = l >> 4, lk = lg * 8;

    const int sa = t >> 2, ska = (t & 3) * 16;
    const int sb = t >> 1, skb = (t & 1) * 32;
    const _Float16* __restrict__ aRow = &A [(size_t)(brow + sa) * 512 + ska];
    const _Float16* __restrict__ bRow = &Bw[(size_t)(bcol + sb) * 512 + skb];
    _Float16* aDst = &As[sa * 72 + ska];
    _Float16* bDst = &Bs[sb * 72 + skb];

    f4 acc[2][4] = {};
    h8 axr[2], bxr[4];

#pragma unroll
    for (int j = 0; j < 2; j++) axr[j] = *reinterpret_cast<const h8*>(&aRow[j * 8]);
#pragma unroll
    for (int j = 0; j < 4; j++) bxr[j] = *reinterpret_cast<const h8*>(&bRow[j * 8]);
#pragma unroll
    for (int j = 0; j < 2; j++) *reinterpret_cast<h8*>(&aDst[j * 8]) = axr[j];
#pragma unroll
    for (int j = 0; j < 4; j++) *reinterpret_cast<h8*>(&bDst[j * 8]) = bxr[j];

    for (int k0 = 0; k0 < 512; k0 += 64) {
        __syncthreads();
        const bool more = (k0 + 64) < 512;
        if (more) {
            const int kn = k0 + 64;
#pragma unroll
            for (int j = 0; j < 2; j++) axr[j] = *reinterpret_cast<const h8*>(&aRow[kn + j * 8]);
#pragma unroll
            for (int j = 0; j < 4; j++) bxr[j] = *reinterpret_cast<const h8*>(&bRow[kn + j * 8]);
        }
#pragma unroll
        for (int ks = 0; ks < 64; ks += 32) {
            h8 af[2], bf[4];
#pragma unroll
            for (int m = 0; m < 2; m++)
                af[m] = *reinterpret_cast<h8*>(&As[(wr + m * 16 + lr) * 72 + ks + lk]);
#pragma unroll
            for (int n = 0; n < 4; n++)
                bf[n] = *reinterpret_cast<h8*>(&Bs[(wc + n * 16 + lr) * 72 + ks + lk]);
            __builtin_amdgcn_s_setprio(1);
#pragma unroll
            for (int m = 0; m < 2; m++)
#pragma unroll
                for (int n = 0; n < 4; n++)
                    acc[m][n] = __builtin_amdgcn_mfma_f32_16x16x32_f16(af[m], bf[n], acc[m][n], 0, 0, 0);
            __builtin_amdgcn_s_setprio(0);
        }
        __syncthreads();
        if (more) {
#pragma unroll
            for (int j = 0; j < 2; j++) *reinterpret_cast<h8*>(&aDst[j * 8]) = axr[j];
#pragma unroll
            for (int j = 0; j < 4; j++) *reinterpret_cast<h8*>(&bDst[j * 8]) = bxr[j];
        }
    }

#pragma unroll
    for (int m = 0; m < 2; m++) {
        const int rloc = wr + m * 16 + lg * 4;
#pragma unroll
        for (int reg = 0; reg < 4; reg++) {
            const size_t base = (size_t)(brow + rloc + reg) * 512 + bcol;
#pragma unroll
            for (int nn = 0; nn < 4; nn++)
                C[base + wc + nn * 16 + lr] = acc[m][nn][reg];
        }
    }
}

extern "C" void kernel_launch(void* const* d_in, const int* in_sizes, int n_in,
                              void* d_out, int out_size, void* d_ws, size_t ws_size,
                              hipStream_t stream)
{
    // interleaved inputs: x0,m0,Wqkv0,Wout0, x1,m1,Wqkv1,Wout1, x2,m2,Wqkv2,Wout2
    const float* x0  = (const float*)d_in[0];
    const int*   m0  = (const int*)  d_in[1];
    const float* Wq0 = (const float*)d_in[2];
    const float* Wo0 = (const float*)d_in[3];
    const float* x1  = (const float*)d_in[4];
    const int*   m1  = (const int*)  d_in[5];
    const float* Wq1 = (const float*)d_in[6];
    const float* Wo1 = (const float*)d_in[7];
    const float* x2  = (const float*)d_in[8];
    const int*   m2  = (const int*)  d_in[9];
    const float* Wq2 = (const float*)d_in[10];
    const float* Wo2 = (const float*)d_in[11];

    _Float16* Wqt = (_Float16*)d_ws;       // 2359296
    _Float16* Wot = Wqt + 2359296;         //  786432
    _Float16* Qh  = Wot + 786432;          // 6291456
    _Float16* Kh  = Qh  + 6291456;         // 6291456
    _Float16* Vt  = Kh  + 6291456;         // 6291456
    _Float16* Oh  = Vt  + 6291456;         // 6291456

    wt_cvt<<<dim3(1024, 1, 3), 256, 0, stream>>>(Wq0, Wq1, Wq2, Wo0, Wo1, Wo2, Wqt, Wot);
    qkv_gemm_f16<<<dim3(32, 12, 3), 256, 0, stream>>>(x0, x1, x2, Wqt, Qh, Kh, Vt);
    attn_f16    <<<dim3(64, 4, 3), 128, 0, stream>>>(Qh, Kh, Vt, m0, m1, m2, Oh);
    out_gemm_f16<<<dim3(64, 4, 3), 256, 0, stream>>>(Oh, Wot, (float*)d_out);
}

// Round 9
// 264.029 us; speedup vs baseline: 1.1472x; 1.1472x over previous
//
#include <hip/hip_runtime.h>
#include <cstdint>
#include <cstddef>

#define NEGV  -1.0e9f
// 0.125 * log2(e): attention computed in exp2 units
#define QSCALE 0.18033688011112042f

typedef _Float16 h8 __attribute__((ext_vector_type(8)));
typedef _Float16 h4 __attribute__((ext_vector_type(4)));
typedef float    f4 __attribute__((ext_vector_type(4)));
typedef float    f16x __attribute__((ext_vector_type(16)));
typedef unsigned int u32x4 __attribute__((ext_vector_type(4)));

// ---------------------------------------------------------------------------
// ws layout (f16 elements):
//  Wqt: [3][1536][512]  (W^T)   2359296
//  Wot: [3][512][512]   (W^T)    786432
//  Qh : [3][8][8][512][64] (q*QSCALE)  6291456
//  Kh : [8][8][1536][64]        6291456
//  Vt : [8][8][64][1536] (V^T)  6291456
//  Oh : [3][4096][512]          6291456
// ---------------------------------------------------------------------------

static __device__ inline h8 cvt8(float4 a, float4 b) {
    h8 r = { (_Float16)a.x, (_Float16)a.y, (_Float16)a.z, (_Float16)a.w,
             (_Float16)b.x, (_Float16)b.y, (_Float16)b.z, (_Float16)b.w };
    return r;
}

// ========== merged W transpose+cvt: Wqkv (512x1536) and Wout (512x512) ==========
__global__ __launch_bounds__(256) void wt_cvt(
    const float* __restrict__ q0, const float* __restrict__ q1, const float* __restrict__ q2,
    const float* __restrict__ o0, const float* __restrict__ o1, const float* __restrict__ o2,
    _Float16* __restrict__ Wqt, _Float16* __restrict__ Wot)
{
    const int mod = blockIdx.z;
    const int flat = blockIdx.x;
    const float* s;
    _Float16* d;
    int C, bx, by;
    if (flat < 768) {
        C = 1536; bx = flat % 48; by = flat / 48;
        s = (mod == 0) ? q0 : ((mod == 1) ? q1 : q2);
        d = Wqt + (size_t)mod * 1536 * 512;
    } else {
        C = 512; bx = (flat - 768) % 16; by = (flat - 768) / 16;
        s = (mod == 0) ? o0 : ((mod == 1) ? o1 : o2);
        d = Wot + (size_t)mod * 512 * 512;
    }
    const int c0 = bx * 32, r0 = by * 32;
    __shared__ float tile[32][33];
    const int tr = threadIdx.x >> 3;
    const int tc = (threadIdx.x & 7) * 4;
    float4 v = *reinterpret_cast<const float4*>(&s[(size_t)(r0 + tr) * C + c0 + tc]);
    tile[tr][tc + 0] = v.x; tile[tr][tc + 1] = v.y; tile[tr][tc + 2] = v.z; tile[tr][tc + 3] = v.w;
    __syncthreads();
    h4 o = { (_Float16)tile[tc + 0][tr], (_Float16)tile[tc + 1][tr],
             (_Float16)tile[tc + 2][tr], (_Float16)tile[tc + 3][tr] };
    *reinterpret_cast<h4*>(&d[(size_t)(c0 + tr) * 512 + r0 + tc]) = o;
}

// ======================= QKV projection (f16 MFMA, BK=64) =======================
__global__ __launch_bounds__(256) void qkv_gemm_f16(
    const float* __restrict__ x0, const float* __restrict__ x1, const float* __restrict__ x2,
    const _Float16* __restrict__ Wqt,
    _Float16* __restrict__ Qh, _Float16* __restrict__ Kh, _Float16* __restrict__ Vt)
{
    const int mod = blockIdx.z;
    const float* __restrict__ A = (mod == 0) ? x0 : ((mod == 1) ? x1 : x2);
    const _Float16* __restrict__ Bw = Wqt + (size_t)mod * 1536 * 512;

    __shared__ _Float16 smem[2 * 128 * 72];   // 36864 B
    _Float16* As = smem;                 // [m][k] stride 72
    _Float16* Bs = smem + 128 * 72;      // [n][k]

    const int t = threadIdx.x;
    const int brow = blockIdx.x * 128, bcol = blockIdx.y * 128;
    const int w = t >> 6, l = t & 63;
    const int wr = (w >> 1) * 64, wc = (w & 1) * 64;
    const int lr = l & 15, lg = l >> 4, lk = lg * 8;

    const int sm = t >> 1, sk = (t & 1) * 32;
    const float*    __restrict__ aRow = &A [(size_t)(brow + sm) * 512 + sk];
    const _Float16* __restrict__ bRow = &Bw[(size_t)(bcol + sm) * 512 + sk];
    _Float16* aDst = &As[sm * 72 + sk];
    _Float16* bDst = &Bs[sm * 72 + sk];

    f4 acc[4][4] = {};
    float4 ax[8];
    h8 bx[4];

#pragma unroll
    for (int j = 0; j < 8; j++) ax[j] = *reinterpret_cast<const float4*>(&aRow[j * 4]);
#pragma unroll
    for (int j = 0; j < 4; j++) bx[j] = *reinterpret_cast<const h8*>(&bRow[j * 8]);
#pragma unroll
    for (int j = 0; j < 4; j++) {
        *reinterpret_cast<h8*>(&aDst[j * 8]) = cvt8(ax[2 * j], ax[2 * j + 1]);
        *reinterpret_cast<h8*>(&bDst[j * 8]) = bx[j];
    }

    for (int k0 = 0; k0 < 512; k0 += 64) {
        __syncthreads();
        const bool more = (k0 + 64) < 512;
        if (more) {
            const int kn = k0 + 64;
#pragma unroll
            for (int j = 0; j < 8; j++) ax[j] = *reinterpret_cast<const float4*>(&aRow[kn + j * 4]);
#pragma unroll
            for (int j = 0; j < 4; j++) bx[j] = *reinterpret_cast<const h8*>(&bRow[kn + j * 8]);
        }
#pragma unroll
        for (int ks = 0; ks < 64; ks += 32) {
            h8 af[4], bf[4];
#pragma unroll
            for (int m = 0; m < 4; m++)
                af[m] = *reinterpret_cast<h8*>(&As[(wr + m * 16 + lr) * 72 + ks + lk]);
#pragma unroll
            for (int n = 0; n < 4; n++)
                bf[n] = *reinterpret_cast<h8*>(&Bs[(wc + n * 16 + lr) * 72 + ks + lk]);
            __builtin_amdgcn_s_setprio(1);
#pragma unroll
            for (int m = 0; m < 4; m++)
#pragma unroll
                for (int n = 0; n < 4; n++)
                    acc[m][n] = __builtin_amdgcn_mfma_f32_16x16x32_f16(af[m], bf[n], acc[m][n], 0, 0, 0);
            __builtin_amdgcn_s_setprio(0);
        }
        __syncthreads();
        if (more) {
#pragma unroll
            for (int j = 0; j < 4; j++) {
                *reinterpret_cast<h8*>(&aDst[j * 8]) = cvt8(ax[2 * j], ax[2 * j + 1]);
                *reinterpret_cast<h8*>(&bDst[j * 8]) = bx[j];
            }
        }
    }

    const int sec = bcol >> 9;                    // 0=q 1=k 2=v
    const int b = brow >> 9;
    const int nbase = brow & 511;
    const int cbase = bcol - (sec << 9);

    if (sec == 2) {
#pragma unroll
        for (int m = 0; m < 4; m++) {
            const int n = nbase + wr + m * 16 + lg * 4;
#pragma unroll
            for (int nn = 0; nn < 4; nn++) {
                const int cis = cbase + wc + nn * 16 + lr;
                const int hh = cis >> 6, d = cis & 63;
                h4 pv = { (_Float16)acc[m][nn][0], (_Float16)acc[m][nn][1],
                          (_Float16)acc[m][nn][2], (_Float16)acc[m][nn][3] };
                *reinterpret_cast<h4*>(&Vt[(((size_t)b * 8 + hh) * 64 + d) * 1536 + mod * 512 + n]) = pv;
            }
        }
    } else {
        const float scl = (sec == 0) ? QSCALE : 1.0f;
        _Float16 (*Ts)[136] = reinterpret_cast<_Float16(*)[136]>(smem);
#pragma unroll
        for (int pass = 0; pass < 2; pass++) {
            __syncthreads();
            if ((w >> 1) == pass) {
#pragma unroll
                for (int m = 0; m < 4; m++)
#pragma unroll
                    for (int nn = 0; nn < 4; nn++)
#pragma unroll
                        for (int reg = 0; reg < 4; reg++)
                            Ts[m * 16 + lg * 4 + reg][wc + nn * 16 + lr] =
                                (_Float16)(acc[m][nn][reg] * scl);
            }
            __syncthreads();
#pragma unroll
            for (int it = 0; it < 4; it++) {
                const int idx = t + it * 256;
                const int rr = idx >> 4, c = (idx & 15) * 8;
                h8 v = *reinterpret_cast<h8*>(&Ts[rr][c]);
                const int n = nbase + pass * 64 + rr;
                const int cis = cbase + c;
                const int hh = cis >> 6, d = cis & 63;
                if (sec == 0)
                    *reinterpret_cast<h8*>(&Qh[((((size_t)mod * 8 + b) * 8 + hh) * 512 + n) * 64 + d]) = v;
                else
                    *reinterpret_cast<h8*>(&Kh[(((size_t)b * 8 + hh) * 1536 + mod * 512 + n) * 64 + d]) = v;
            }
        }
    }
}

// ======================= attention: 32x32 MFMA, K+V in LDS, P in registers =======================
// block: 256 thr = 4 waves; wave w owns 32 q rows. QBLK=128.
// grid (bh, 4 qtiles, mod): bh-major keeps K/V sharers on one XCD.
// Ks stride-72 rows (bank-balanced); Vs XOR-swizzled; P via cvt_pkrtz + shfl_xor(32).
__global__ __launch_bounds__(256) void attn_f16(
    const _Float16* __restrict__ Qh, const _Float16* __restrict__ Kh, const _Float16* __restrict__ Vt,
    const int* __restrict__ m0, const int* __restrict__ m1, const int* __restrict__ m2,
    _Float16* __restrict__ Oh)
{
    const int mod = blockIdx.z;
    const int bh = blockIdx.x, b = bh >> 3, h = bh & 7;
    const int q0 = blockIdx.y * 128;

    __shared__ _Float16 Ks[64 * 72];   // [key][d] stride 72
    __shared__ _Float16 Vs[64 * 64];   // [d][key] XOR-swizzled 16B segs

    const int t = threadIdx.x, w = t >> 6, l = t & 63;
    const int r = l & 31, hi = l >> 5;

    // Q B-frags: lane holds Q[q = w*32 + r][dk*16 + hi*8 ..+7]
    const _Float16* __restrict__ Qp = Qh + ((((size_t)mod * 8 + b) * 8 + h) * 512 + q0 + w * 32) * 64;
    h8 qf[4];
#pragma unroll
    for (int dk = 0; dk < 4; dk++)
        qf[dk] = *reinterpret_cast<const h8*>(&Qp[(size_t)r * 64 + dk * 16 + hi * 8]);

    const int* __restrict__ mk = (mod == 0) ? m0 : ((mod == 1) ? m1 : m2);
    const bool msk = mk[b * 512 + q0 + w * 32 + r] != 0;

    float mrow = -3.0e38f, lsum = 0.f;
    f16x o[2] = {};   // [dg]: O^T[d = dg*32 + (reg&3)+8*(reg>>2)+4*hi][q = r]

    const _Float16* __restrict__ Kp = Kh + (size_t)bh * 1536 * 64;
    const _Float16* __restrict__ Vp = Vt + (size_t)bh * 64 * 1536;

    // staging: thread covers row sr (0..63), two 16B segs s2, s2+1
    const int sr = t >> 2, s2 = (t & 3) * 2;

    h8 krg[2], vrg[2];
#pragma unroll
    for (int j = 0; j < 2; j++) {
        krg[j] = *reinterpret_cast<const h8*>(&Kp[(size_t)sr * 64 + (s2 + j) * 8]);
        vrg[j] = *reinterpret_cast<const h8*>(&Vp[(size_t)sr * 1536 + (s2 + j) * 8]);
    }
#pragma unroll
    for (int j = 0; j < 2; j++) {
        *reinterpret_cast<h8*>(&Ks[sr * 72 + (s2 + j) * 8]) = krg[j];
        *reinterpret_cast<h8*>(&Vs[sr * 64 + (((s2 + j) ^ (sr & 7)) * 8)]) = vrg[j];
    }

    for (int c0 = 0; c0 < 1536; c0 += 64) {
        __syncthreads();                       // staged K/V visible
        const bool more = (c0 + 64) < 1536;
        if (more) {                            // issue next-chunk loads early
            const int cn = c0 + 64;
#pragma unroll
            for (int j = 0; j < 2; j++) {
                krg[j] = *reinterpret_cast<const h8*>(&Kp[(size_t)(cn + sr) * 64 + (s2 + j) * 8]);
                vrg[j] = *reinterpret_cast<const h8*>(&Vp[(size_t)sr * 1536 + cn + (s2 + j) * 8]);
            }
        }

#pragma unroll
        for (int s32 = 0; s32 < 2; s32++) {
            // K A-frags from LDS (shared across the block's 4 waves)
            h8 kc[4];
#pragma unroll
            for (int dk = 0; dk < 4; dk++)
                kc[dk] = *reinterpret_cast<h8*>(&Ks[(s32 * 32 + r) * 72 + dk * 16 + hi * 8]);

            // S^T = K Q^T : C[row=key(reg,hi)][col=q=r]
            f16x st = {};
            __builtin_amdgcn_s_setprio(1);
#pragma unroll
            for (int dk = 0; dk < 4; dk++)
                st = __builtin_amdgcn_mfma_f32_32x32x16_f16(kc[dk], qf[dk], st, 0, 0, 0);
            __builtin_amdgcn_s_setprio(0);

            if (!msk) {
#pragma unroll
                for (int reg = 0; reg < 16; reg++) st[reg] = NEGV;
            }
            float cm = st[0];
#pragma unroll
            for (int reg = 1; reg < 16; reg++) cm = fmaxf(cm, st[reg]);
            cm = fmaxf(cm, __shfl_xor(cm, 32));

            if (!__all(cm <= mrow + 8.0f)) {   // defer-max
                const float mn = fmaxf(mrow, cm);
                const float sc = __builtin_amdgcn_exp2f(mrow - mn);
                mrow = mn;
                lsum *= sc;
                o[0] *= sc;
                o[1] *= sc;
            }

            float p[16];
            float rs = 0.f;
#pragma unroll
            for (int reg = 0; reg < 16; reg++) {
                p[reg] = __builtin_amdgcn_exp2f(st[reg] - mrow);
                rs += p[reg];
            }
            rs += __shfl_xor(rs, 32);
            lsum += rs;

            // P B-frag assembly (verified in R8): keys kk*16 + hi*8 + j
            u32x4 pbw[2];
#pragma unroll
            for (int kk = 0; kk < 2; kk++) {
                unsigned int a0 = __builtin_bit_cast(unsigned int,
                    __builtin_amdgcn_cvt_pkrtz(p[8 * kk + 0], p[8 * kk + 1]));
                unsigned int a1 = __builtin_bit_cast(unsigned int,
                    __builtin_amdgcn_cvt_pkrtz(p[8 * kk + 2], p[8 * kk + 3]));
                unsigned int b0 = __builtin_bit_cast(unsigned int,
                    __builtin_amdgcn_cvt_pkrtz(p[8 * kk + 4], p[8 * kk + 5]));
                unsigned int b1 = __builtin_bit_cast(unsigned int,
                    __builtin_amdgcn_cvt_pkrtz(p[8 * kk + 6], p[8 * kk + 7]));
                const unsigned int ra0 = __shfl_xor(a0, 32);
                const unsigned int ra1 = __shfl_xor(a1, 32);
                const unsigned int rb0 = __shfl_xor(b0, 32);
                const unsigned int rb1 = __shfl_xor(b1, 32);
                u32x4 pw;
                if (hi == 0) { pw[0] = a0; pw[1] = a1; pw[2] = ra0; pw[3] = ra1; }
                else         { pw[0] = rb0; pw[1] = rb1; pw[2] = b0; pw[3] = b1; }
                pbw[kk] = pw;
            }

            // O^T += V^T P : A = V^T[32 d][16 k] from swizzled LDS
            __builtin_amdgcn_s_setprio(1);
#pragma unroll
            for (int kk = 0; kk < 2; kk++) {
                const h8 pb = __builtin_bit_cast(h8, pbw[kk]);
#pragma unroll
                for (int dg = 0; dg < 2; dg++) {
                    h8 va = *reinterpret_cast<h8*>(
                        &Vs[(dg * 32 + r) * 64 + (((s32 * 4 + kk * 2 + hi) ^ (r & 7)) * 8)]);
                    o[dg] = __builtin_amdgcn_mfma_f32_32x32x16_f16(va, pb, o[dg], 0, 0, 0);
                }
            }
            __builtin_amdgcn_s_setprio(0);
        }

        __syncthreads();                       // all K/V reads done
        if (more) {                            // write-late
#pragma unroll
            for (int j = 0; j < 2; j++) {
                *reinterpret_cast<h8*>(&Ks[sr * 72 + (s2 + j) * 8]) = krg[j];
                *reinterpret_cast<h8*>(&Vs[sr * 64 + (((s2 + j) ^ (sr & 7)) * 8)]) = vrg[j];
            }
        }
    }

    // store O: lane holds O^T[d = dg*32 + (reg&3)+8*(reg>>2)+4*hi][q = r]
    const float inv = 1.f / lsum;
    const size_t row = (size_t)mod * 4096 + b * 512 + q0 + w * 32 + r;
#pragma unroll
    for (int dg = 0; dg < 2; dg++)
#pragma unroll
        for (int a = 0; a < 4; a++) {
            h4 ov = { (_Float16)(o[dg][4 * a + 0] * inv),
                      (_Float16)(o[dg][4 * a + 1] * inv),
                      (_Float16)(o[dg][4 * a + 2] * inv),
                      (_Float16)(o[dg][4 * a + 3] * inv) };
            *reinterpret_cast<h4*>(&Oh[row * 512 + h * 64 + dg * 32 + a * 8 + hi * 4]) = ov;
        }
}

// ======================= output projection (BM=64, BN=128, BK=64) =======================
__global__ __launch_bounds__(256) void out_gemm_f16(
    const _Float16* __restrict__ Oh, const _Float16* __restrict__ Wot,
    float* __restrict__ out)
{
    const int mod = blockIdx.z;
    const _Float16* __restrict__ A  = Oh  + (size_t)mod * 4096 * 512;
    const _Float16* __restrict__ Bw = Wot + (size_t)mod * 512 * 512;
    float* __restrict__ C = out + (size_t)mod * 4096 * 512;

    __shared__ _Float16 smem[(64 + 128) * 72];   // 27648 B
    _Float16* As = smem;                 // [m 64][k 72]
    _Float16* Bs = smem + 64 * 72;       // [n 128][k 72]

    const int t = threadIdx.x;
    const int brow = blockIdx.x * 64, bcol = blockIdx.y * 128;
    const int w = t >> 6, l = t & 63;
    const int wr = (w >> 1) * 32, wc = (w & 1) * 64;
    const int lr = l & 15, lg = l >> 4, lk = lg * 8;

    const int sa = t >> 2, ska = (t & 3) * 16;
    const int sb = t >> 1, skb = (t & 1) * 32;
    const _Float16* __restrict__ aRow = &A [(size_t)(brow + sa) * 512 + ska];
    const _Float16* __restrict__ bRow = &Bw[(size_t)(bcol + sb) * 512 + skb];
    _Float16* aDst = &As[sa * 72 + ska];
    _Float16* bDst = &Bs[sb * 72 + skb];

    f4 acc[2][4] = {};
    h8 axr[2], bxr[4];

#pragma unroll
    for (int j = 0; j < 2; j++) axr[j] = *reinterpret_cast<const h8*>(&aRow[j * 8]);
#pragma unroll
    for (int j = 0; j < 4; j++) bxr[j] = *reinterpret_cast<const h8*>(&bRow[j * 8]);
#pragma unroll
    for (int j = 0; j < 2; j++) *reinterpret_cast<h8*>(&aDst[j * 8]) = axr[j];
#pragma unroll
    for (int j = 0; j < 4; j++) *reinterpret_cast<h8*>(&bDst[j * 8]) = bxr[j];

    for (int k0 = 0; k0 < 512; k0 += 64) {
        __syncthreads();
        const bool more = (k0 + 64) < 512;
        if (more) {
            const int kn = k0 + 64;
#pragma unroll
            for (int j = 0; j < 2; j++) axr[j] = *reinterpret_cast<const h8*>(&aRow[kn + j * 8]);
#pragma unroll
            for (int j = 0; j < 4; j++) bxr[j] = *reinterpret_cast<const h8*>(&bRow[kn + j * 8]);
        }
#pragma unroll
        for (int ks = 0; ks < 64; ks += 32) {
            h8 af[2], bf[4];
#pragma unroll
            for (int m = 0; m < 2; m++)
                af[m] = *reinterpret_cast<h8*>(&As[(wr + m * 16 + lr) * 72 + ks + lk]);
#pragma unroll
            for (int n = 0; n < 4; n++)
                bf[n] = *reinterpret_cast<h8*>(&Bs[(wc + n * 16 + lr) * 72 + ks + lk]);
            __builtin_amdgcn_s_setprio(1);
#pragma unroll
            for (int m = 0; m < 2; m++)
#pragma unroll
                for (int n = 0; n < 4; n++)
                    acc[m][n] = __builtin_amdgcn_mfma_f32_16x16x32_f16(af[m], bf[n], acc[m][n], 0, 0, 0);
            __builtin_amdgcn_s_setprio(0);
        }
        __syncthreads();
        if (more) {
#pragma unroll
            for (int j = 0; j < 2; j++) *reinterpret_cast<h8*>(&aDst[j * 8]) = axr[j];
#pragma unroll
            for (int j = 0; j < 4; j++) *reinterpret_cast<h8*>(&bDst[j * 8]) = bxr[j];
        }
    }

#pragma unroll
    for (int m = 0; m < 2; m++) {
        const int rloc = wr + m * 16 + lg * 4;
#pragma unroll
        for (int reg = 0; reg < 4; reg++) {
            const size_t base = (size_t)(brow + rloc + reg) * 512 + bcol;
#pragma unroll
            for (int nn = 0; nn < 4; nn++)
                C[base + wc + nn * 16 + lr] = acc[m][nn][reg];
        }
    }
}

extern "C" void kernel_launch(void* const* d_in, const int* in_sizes, int n_in,
                              void* d_out, int out_size, void* d_ws, size_t ws_size,
                              hipStream_t stream)
{
    // interleaved inputs: x0,m0,Wqkv0,Wout0, x1,m1,Wqkv1,Wout1, x2,m2,Wqkv2,Wout2
    const float* x0  = (const float*)d_in[0];
    const int*   m0  = (const int*)  d_in[1];
    const float* Wq0 = (const float*)d_in[2];
    const float* Wo0 = (const float*)d_in[3];
    const float* x1  = (const float*)d_in[4];
    const int*   m1  = (const int*)  d_in[5];
    const float* Wq1 = (const float*)d_in[6];
    const float* Wo1 = (const float*)d_in[7];
    const float* x2  = (const float*)d_in[8];
    const int*   m2  = (const int*)  d_in[9];
    const float* Wq2 = (const float*)d_in[10];
    const float* Wo2 = (const float*)d_in[11];

    _Float16* Wqt = (_Float16*)d_ws;       // 2359296
    _Float16* Wot = Wqt + 2359296;         //  786432
    _Float16* Qh  = Wot + 786432;          // 6291456
    _Float16* Kh  = Qh  + 6291456;         // 6291456
    _Float16* Vt  = Kh  + 6291456;         // 6291456
    _Float16* Oh  = Vt  + 6291456;         // 6291456

    wt_cvt<<<dim3(1024, 1, 3), 256, 0, stream>>>(Wq0, Wq1, Wq2, Wo0, Wo1, Wo2, Wqt, Wot);
    qkv_gemm_f16<<<dim3(32, 12, 3), 256, 0, stream>>>(x0, x1, x2, Wqt, Qh, Kh, Vt);
    attn_f16    <<<dim3(64, 4, 3), 256, 0, stream>>>(Qh, Kh, Vt, m0, m1, m2, Oh);
    out_gemm_f16<<<dim3(64, 4, 3), 256, 0, stream>>>(Oh, Wot, (float*)d_out);
}